// Round 6
// baseline (372.213 us; speedup 1.0000x reference)
//
#include <hip/hip_runtime.h>

#define NI 4096
#define NH 8192
#define NO 2048
#define NBLK 512
#define NWAVE (NBLK * 4)   // 2048 waves

typedef float f4 __attribute__((ext_vector_type(4)));

__device__ __forceinline__ float apply_act(float x, int id) {
    switch (id) {
        case 0:  return x;
        case 1:  return x >= 0.f ? x : 0.01f * x;   // leaky_relu
        case 2:  return fmaxf(x, 0.f);              // relu
        case 3:  return 1.f / (1.f + expf(-x));     // sigmoid
        default: return tanhf(x);                   // tanh
    }
}

// One 64-lane wave: dot(Wrow, x), float4 loads, butterfly reduce (R2 shape).
template <bool NT>
__device__ __forceinline__ float wave_dot(const float* __restrict__ Wrow,
                                          const float* __restrict__ x,
                                          int K, int lane) {
    const f4* __restrict__ W4 = (const f4*)Wrow;
    const f4* __restrict__ x4 = (const f4*)x;
    float acc = 0.f;
    const int n4 = K >> 2;
    #pragma unroll 4
    for (int i = lane; i < n4; i += 64) {
        f4 w = NT ? __builtin_nontemporal_load(W4 + i) : W4[i];
        f4 v = x4[i];
        acc = fmaf(w.x, v.x, acc);
        acc = fmaf(w.y, v.y, acc);
        acc = fmaf(w.z, v.z, acc);
        acc = fmaf(w.w, v.w, acc);
    }
    #pragma unroll
    for (int off = 32; off; off >>= 1) acc += __shfl_xor(acc, off, 64);
    return acc;
}

// Grid-wide barrier: agent-scope arrive counter + release/acquire flag.
// cnt/flag zeroed by hipMemsetAsync before each launch (replay-safe).
__device__ __forceinline__ void grid_barrier(int* cnt, int* flag) {
    __syncthreads();
    if (threadIdx.x == 0) {
        int old = __hip_atomic_fetch_add(cnt, 1, __ATOMIC_ACQ_REL,
                                         __HIP_MEMORY_SCOPE_AGENT);
        if (old == (int)gridDim.x - 1) {
            __hip_atomic_store(flag, 1, __ATOMIC_RELEASE,
                               __HIP_MEMORY_SCOPE_AGENT);
        } else {
            while (!__hip_atomic_load(flag, __ATOMIC_ACQUIRE,
                                      __HIP_MEMORY_SCOPE_AGENT))
                __builtin_amdgcn_s_sleep(1);
        }
    }
    __syncthreads();
}

__global__ __launch_bounds__(256, 2) void k_fused(
        const float* __restrict__ xin,
        const float* __restrict__ W_i2h,
        const float* __restrict__ W_h2h,
        const float* __restrict__ W_o2h,
        const float* __restrict__ W_i2o,
        const float* __restrict__ W_h2o,
        const float* __restrict__ W_o2o,
        const float* __restrict__ h_resp,
        const float* __restrict__ h_bias,
        const float* __restrict__ o_resp,
        const float* __restrict__ o_bias,
        const float* __restrict__ a0,
        const float* __restrict__ o0,
        const int* __restrict__ h_ids,
        const int* __restrict__ o_ids,
        float* __restrict__ c_h,
        float* __restrict__ act_a,
        float* __restrict__ act_b,
        float* __restrict__ act_c,
        int* __restrict__ flags,
        int* __restrict__ bar,
        float* __restrict__ out) {
    const int wave = threadIdx.x >> 6;
    const int lane = threadIdx.x & 63;
    const int gw = blockIdx.x * 4 + wave;   // 0 .. NWAVE-1

    // ---- phase 0: zero-vector flags (one atomic per wave max) ----
    {
        int gtid = blockIdx.x * 256 + threadIdx.x;
        int gsz = NBLK * 256;
        int f0 = 0, f1 = 0, f2 = 0;
        for (int i = gtid; i < NI; i += gsz) f0 |= (xin[i] != 0.f);
        for (int i = gtid; i < NH; i += gsz) f1 |= (a0[i]  != 0.f);
        for (int i = gtid; i < NO; i += gsz) f2 |= (o0[i]  != 0.f);
        if (__any(f0) && lane == 0) atomicOr(flags + 0, 1);
        if (__any(f1) && lane == 0) atomicOr(flags + 1, 1);
        if (__any(f2) && lane == 0) atomicOr(flags + 2, 1);
    }
    grid_barrier(bar + 0, bar + 4);
    const int f0 = flags[0], f1 = flags[1], f2 = flags[2];

    // ---- phase 1: c_h (loop-invariant) + step-1 epilogue ----
    #pragma unroll
    for (int p = 0; p < NH / NWAVE; ++p) {
        int m = gw + p * NWAVE;
        float c = 0.f;
        if (f0) c += wave_dot<true>(W_i2h + (size_t)m * NI, xin, NI, lane);
        if (f2) c += wave_dot<true>(W_o2h + (size_t)m * NO, o0,  NO, lane);
        float d = 0.f;
        if (f1) d = wave_dot<true>(W_h2h + (size_t)m * NH, a0, NH, lane);
        if (lane == 0) {
            c_h[m] = c;
            act_a[m] = apply_act(fmaf(h_resp[m], c + d, h_bias[m]), h_ids[m]);
        }
    }
    grid_barrier(bar + 1, bar + 5);

    // ---- phase 2: step 2 ----
    #pragma unroll
    for (int p = 0; p < NH / NWAVE; ++p) {
        int m = gw + p * NWAVE;
        float d = wave_dot<true>(W_h2h + (size_t)m * NH, act_a, NH, lane);
        if (lane == 0)
            act_b[m] = apply_act(fmaf(h_resp[m], c_h[m] + d, h_bias[m]), h_ids[m]);
    }
    grid_barrier(bar + 2, bar + 6);

    // ---- phase 3: step 3 ----
    #pragma unroll
    for (int p = 0; p < NH / NWAVE; ++p) {
        int m = gw + p * NWAVE;
        float d = wave_dot<true>(W_h2h + (size_t)m * NH, act_b, NH, lane);
        if (lane == 0)
            act_c[m] = apply_act(fmaf(h_resp[m], c_h[m] + d, h_bias[m]), h_ids[m]);
    }
    grid_barrier(bar + 3, bar + 7);

    // ---- phase 4: output layer (1 row per wave) ----
    {
        int m = gw;   // NWAVE == NO
        float dot = wave_dot<true>(W_h2o + (size_t)m * NH, act_c, NH, lane);
        if (f0) dot += wave_dot<true>(W_i2o + (size_t)m * NI, xin, NI, lane);
        if (f2) dot += wave_dot<true>(W_o2o + (size_t)m * NO, o0,  NO, lane);
        if (lane == 0)
            out[m] = apply_act(fmaf(o_resp[m], dot, o_bias[m]), o_ids[m]);
    }
}

extern "C" void kernel_launch(void* const* d_in, const int* in_sizes, int n_in,
                              void* d_out, int out_size, void* d_ws, size_t ws_size,
                              hipStream_t stream) {
    const float* inputs   = (const float*)d_in[0];
    const float* W_i2h    = (const float*)d_in[1];
    const float* W_h2h    = (const float*)d_in[2];
    const float* W_o2h    = (const float*)d_in[3];
    const float* W_i2o    = (const float*)d_in[4];
    const float* W_h2o    = (const float*)d_in[5];
    const float* W_o2o    = (const float*)d_in[6];
    const float* h_resp   = (const float*)d_in[7];
    const float* h_bias   = (const float*)d_in[8];
    const float* o_resp   = (const float*)d_in[9];
    const float* o_bias   = (const float*)d_in[10];
    const float* activs0  = (const float*)d_in[11];
    const float* outputs0 = (const float*)d_in[12];
    const int*   h_ids    = (const int*)d_in[13];
    const int*   o_ids    = (const int*)d_in[14];

    float* ws    = (float*)d_ws;
    float* c_h   = ws;            // NH
    float* act_a = ws + NH;       // NH
    float* act_b = ws + 2 * NH;   // NH
    float* act_c = ws + 3 * NH;   // NH
    int*   ints  = (int*)(ws + 4 * NH);
    int*   flags = ints;          // 3
    int*   bar   = ints + 3;      // 8 (4 cnt + 4 flag)

    // zero flags + barrier state every call (graph replays re-run this)
    hipMemsetAsync(ints, 0, 11 * sizeof(int), stream);

    k_fused<<<NBLK, 256, 0, stream>>>(inputs, W_i2h, W_h2h, W_o2h, W_i2o, W_h2o,
                                      W_o2o, h_resp, h_bias, o_resp, o_bias,
                                      activs0, outputs0, h_ids, o_ids,
                                      c_h, act_a, act_b, act_c, flags, bar,
                                      (float*)d_out);
}